// Round 6
// baseline (825.580 us; speedup 1.0000x reference)
//
#include <hip/hip_runtime.h>

#define NB 512
#define NT 1024
#define NK 48
#define NEGV -10000.0f
#define S_START 46
#define S_END 47

__device__ __forceinline__ float rdlane(float x, int lane) {
    return __int_as_float(__builtin_amdgcn_readlane(__float_as_int(x), lane));
}

extern "C" __global__ __launch_bounds__(128, 1)
void crf_fused(const float* __restrict__ feats, const float* __restrict__ trans,
               float* __restrict__ out)
{
    // wave 0: CRF forward (logZ).  wave 1: Viterbi + backtrace.
    // State broadcast via v_readlane (VALU) -- NO LDS round-trip on the
    // recurrence chain at all. LDS only holds backpointers (wave 1).
    __shared__ unsigned char bp[NT * NK];        // 48 KB backpointers (wave 1)
    __shared__ unsigned char comp[64 * NK];      // composed chunk tag-maps
    __shared__ unsigned char boundary[64];       // chunk-entry tags

    const int b = blockIdx.x;
    const int wave = threadIdx.x >> 6;
    const int lane = threadIdx.x & 63;
    const bool act = lane < NK;
    const int LL = act ? lane : (NK - 1);        // clamped state: lanes 48..63 mirror 47
    const float* f = feats + (size_t)b * NT * NK;
    const float* fb = f + LL;                    // per-lane column base (always in-bounds)

    float tEnd = NEGV;
    if (act && lane != S_END) tEnd = trans[S_END * NK + lane];

    if (wave == 0) {
        // ---------------- forward: u_t = anchored log-alpha; exact 1-step-stale max anchor
        float Erow[NK];
        {
            const bool rowdead = (lane == S_START);
            const float4* r4 = (const float4*)(trans + LL * NK);
            #pragma unroll
            for (int q = 0; q < NK / 4; ++q) {
                float4 r = r4[q];
                const int c = 4 * q;
                Erow[c + 0] = (rowdead || c + 0 == S_END) ? 0.0f : __expf(r.x);
                Erow[c + 1] = (rowdead || c + 1 == S_END) ? 0.0f : __expf(r.y);
                Erow[c + 2] = (rowdead || c + 2 == S_END) ? 0.0f : __expf(r.z);
                Erow[c + 3] = (rowdead || c + 3 == S_END) ? 0.0f : __expf(r.w);
            }
        }
        float u = (lane == S_START) ? 0.0f : NEGV;
        float Muni = 0.0f;
        float bmax = 0.0f;                       // max over lanes of current u (exact)

        float fr0 = fb[0 * NK], fr1 = fb[1 * NK], fr2 = fb[2 * NK], fr3 = fb[3 * NK];

        auto fstep = [&](float fc) {
            float e = __expf(u);                 // per-lane exp(anchored alpha)
            float a0 = 0.f, a1 = 0.f, a2 = 0.f, a3 = 0.f;
            #pragma unroll
            for (int q = 0; q < 12; ++q) {       // readlane all-gather + FMA
                float e0 = rdlane(e, 4 * q + 0);
                float e1 = rdlane(e, 4 * q + 1);
                float e2 = rdlane(e, 4 * q + 2);
                float e3 = rdlane(e, 4 * q + 3);
                a0 = fmaf(Erow[4 * q + 0], e0, a0);   // grouping identical to R1..R5
                a1 = fmaf(Erow[4 * q + 1], e1, a1);
                a2 = fmaf(Erow[4 * q + 2], e2, a2);
                a3 = fmaf(Erow[4 * q + 3], e3, a3);
            }
            float acc = (a0 + a1) + (a2 + a3);
            float dM = bmax;                     // anchor: exact max of u_{t-1} (uniform)
            float w = __logf(acc) + fc;
            u = w - dM;
            // butterfly max of new u; latency hides under next step's readlane/FMA issue
            float bm = u;
            #pragma unroll
            for (int off = 32; off >= 1; off >>= 1)
                bm = fmaxf(bm, __shfl_xor(bm, off, 64));
            bmax = bm;
            Muni += dM;
        };

        for (int t = 0; t < NT; t += 4) {
            { float fc = fr0; int nr = (t + 4 < NT) ? t + 4 : NT - 1; fr0 = fb[nr * NK]; fstep(fc); }
            { float fc = fr1; int nr = (t + 5 < NT) ? t + 5 : NT - 1; fr1 = fb[nr * NK]; fstep(fc); }
            { float fc = fr2; int nr = (t + 6 < NT) ? t + 6 : NT - 1; fr2 = fb[nr * NK]; fstep(fc); }
            { float fc = fr3; int nr = (t + 7 < NT) ? t + 7 : NT - 1; fr3 = fb[nr * NK]; fstep(fc); }
        }
        // logz = Muni + logsumexp(u + tEnd)
        float x = act ? (u + tEnd) : -INFINITY;
        float M2 = x;
        #pragma unroll
        for (int off = 32; off >= 1; off >>= 1)
            M2 = fmaxf(M2, __shfl_xor(M2, off, 64));
        float e = __expf(x - M2);
        #pragma unroll
        for (int off = 32; off >= 1; off >>= 1)
            e += __shfl_xor(e, off, 64);
        if (lane == 0) out[b] = Muni + M2 + __logf(e);
    } else {
        // ---------------- viterbi: exact fp32, reference op order
        float trow[NK];
        {
            const bool rowdead = (lane == S_START);
            const float4* r4 = (const float4*)(trans + LL * NK);
            #pragma unroll
            for (int q = 0; q < NK / 4; ++q) {
                float4 r = r4[q];
                const int c = 4 * q;
                trow[c + 0] = (rowdead || c + 0 == S_END) ? NEGV : r.x;
                trow[c + 1] = (rowdead || c + 1 == S_END) ? NEGV : r.y;
                trow[c + 2] = (rowdead || c + 2 == S_END) ? NEGV : r.z;
                trow[c + 3] = (rowdead || c + 3 == S_END) ? NEGV : r.w;
            }
        }
        float v = (lane == S_START) ? 0.0f : NEGV;

        float fr0 = fb[0 * NK], fr1 = fb[1 * NK], fr2 = fb[2 * NK], fr3 = fb[3 * NK];
        const int big = 63;

        auto vstep = [&](float fc, int tt) {
            float s[NK];
            #pragma unroll
            for (int p = 0; p < NK; ++p)
                s[p] = rdlane(v, p) + trow[p];   // SGPR + VGPR add: legal, full rate
            // exact max via tree (max exactly associative; identical to np.max)
            float m16[16];
            #pragma unroll
            for (int i = 0; i < 16; ++i)
                m16[i] = fmaxf(fmaxf(s[3 * i], s[3 * i + 1]), s[3 * i + 2]);
            float m6[6];
            #pragma unroll
            for (int i = 0; i < 5; ++i)
                m6[i] = fmaxf(fmaxf(m16[3 * i], m16[3 * i + 1]), m16[3 * i + 2]);
            m6[5] = m16[15];
            float best = fmaxf(fmaxf(fmaxf(m6[0], m6[1]), m6[2]),
                               fmaxf(fmaxf(m6[3], m6[4]), m6[5]));

            v = best + fc;                       // reference order: +feat after max
            // off-chain: first-occurrence argmax (np.argmax), then bp store
            int ix[NK];
            #pragma unroll
            for (int p = 0; p < NK; ++p)
                ix[p] = (s[p] != best) ? big : p;
            int n16[16];
            #pragma unroll
            for (int i = 0; i < 16; ++i)
                n16[i] = min(min(ix[3 * i], ix[3 * i + 1]), ix[3 * i + 2]);
            int n6[6];
            #pragma unroll
            for (int i = 0; i < 5; ++i)
                n6[i] = min(min(n16[3 * i], n16[3 * i + 1]), n16[3 * i + 2]);
            n6[5] = n16[15];
            int bi = min(min(min(n6[0], n6[1]), n6[2]),
                         min(min(n6[3], n6[4]), n6[5]));
            bp[tt * NK + LL] = (unsigned char)bi; // lanes 47..63: same addr, same value
        };

        for (int t = 0; t < NT; t += 4) {
            { float fc = fr0; int nr = (t + 4 < NT) ? t + 4 : NT - 1; fr0 = fb[nr * NK]; vstep(fc, t + 0); }
            { float fc = fr1; int nr = (t + 5 < NT) ? t + 5 : NT - 1; fr1 = fb[nr * NK]; vstep(fc, t + 1); }
            { float fc = fr2; int nr = (t + 6 < NT) ? t + 6 : NT - 1; fr2 = fb[nr * NK]; vstep(fc, t + 2); }
            { float fc = fr3; int nr = (t + 7 < NT) ? t + 7 : NT - 1; fr3 = fb[nr * NK]; vstep(fc, t + 3); }
        }
        // termination: term = v + trans[END]; first-occurrence argmax
        float xv = act ? (v + tEnd) : -INFINITY;
        int idx = act ? lane : 63;
        float val = xv;
        #pragma unroll
        for (int off = 32; off >= 1; off >>= 1) {
            float ov = __shfl_xor(val, off, 64);
            int   oi = __shfl_xor(idx, off, 64);
            if (ov > val || (ov == val && oi < idx)) { val = ov; idx = oi; }
        }
        if (lane == 0) out[NB + b] = val;
        const int last = idx;

        // ---- chunk-composed backtrace (all intra-wave LDS, in-order DS pipe)
        __builtin_amdgcn_wave_barrier();
        int cur[NK];
        #pragma unroll
        for (int k = 0; k < NK; ++k) cur[k] = k;
        const int tbase = lane * 16;                 // 64 chunks of 16 steps
        for (int i = 15; i >= 0; --i) {
            const int t = tbase + i;
            #pragma unroll
            for (int k = 0; k < NK; ++k) cur[k] = bp[t * NK + cur[k]];
        }
        #pragma unroll
        for (int k = 0; k < NK; ++k) comp[lane * NK + k] = (unsigned char)cur[k];
        __builtin_amdgcn_wave_barrier();

        if (lane == 0) {                             // serial chase over 64 maps
            int tag = last;
            for (int l = 63; l >= 0; --l) {
                boundary[l] = (unsigned char)tag;
                tag = comp[l * NK + tag];
            }
        }
        __builtin_amdgcn_wave_barrier();

        int tag = boundary[lane];
        float* pout = out + 2 * NB + (size_t)b * NT;
        for (int i = 15; i >= 0; --i) {              // re-expand: path[t]=tag, then step
            const int t = tbase + i;
            pout[t] = (float)tag;
            tag = bp[t * NK + tag];
        }
    }
}

extern "C" void kernel_launch(void* const* d_in, const int* in_sizes, int n_in,
                              void* d_out, int out_size, void* d_ws, size_t ws_size,
                              hipStream_t stream) {
    (void)in_sizes; (void)n_in; (void)d_ws; (void)ws_size; (void)out_size;
    const float* feats = (const float*)d_in[0];
    const float* trans = (const float*)d_in[1];
    float* out = (float*)d_out;
    crf_fused<<<dim3(NB), dim3(128), 0, stream>>>(feats, trans, out);
}

// Round 7
// 634.030 us; speedup vs baseline: 1.3021x; 1.3021x over previous
//
#include <hip/hip_runtime.h>

#define NB 512
#define NT 1024
#define NK 48
#define NEGV -10000.0f
#define S_START 46
#define S_END 47

extern "C" __global__ __launch_bounds__(128, 1)
void crf_fused(const float* __restrict__ feats, const float* __restrict__ trans,
               float* __restrict__ out)
{
    // wave 0: CRF forward (logZ).  wave 1: Viterbi + backtrace.
    // Viterbi step shape (software pipeline, 2-phase s-double-buffer):
    //   issue 12 ds_read_b128 -> [sched fence] -> argmax of PREVIOUS step's s
    //   (hides DS read latency with useful issue) -> [fence] -> adds/max tree
    //   -> v = best + feat -> vbuf store.
    __shared__ unsigned char bp[(NT + 1) * NK]; // row 0 = dummy; step t -> row t+1
    __shared__ unsigned char comp[64 * NK];      // composed chunk tag-maps
    __shared__ unsigned char boundary[64];       // chunk-entry tags
    __shared__ float eabuf[64];                  // forward broadcast buffer
    __shared__ float vbuf[64];                   // viterbi broadcast buffer

    const int b = blockIdx.x;
    const int wave = threadIdx.x >> 6;
    const int lane = threadIdx.x & 63;
    const bool act = lane < NK;
    const int LL = act ? lane : (NK - 1);        // clamped state: lanes 48..63 mirror 47
    const float* f = feats + (size_t)b * NT * NK;
    const float* fb = f + LL;                    // per-lane column base (always in-bounds)

    float tEnd = NEGV;
    if (act && lane != S_END) tEnd = trans[S_END * NK + lane];

    if (wave == 0) {
        // ---------------- forward: alpha' = M + log(E . exp(alpha-M)) + feat
        // M one step stale = EXACT max of prev alpha (absmax-0 lineage R3/R4/R5)
        float Erow[NK];
        {
            const bool rowdead = (lane == S_START);
            const float4* r4 = (const float4*)(trans + LL * NK);
            #pragma unroll
            for (int q = 0; q < NK / 4; ++q) {
                float4 r = r4[q];
                const int c = 4 * q;
                Erow[c + 0] = (rowdead || c + 0 == S_END) ? 0.0f : __expf(r.x);
                Erow[c + 1] = (rowdead || c + 1 == S_END) ? 0.0f : __expf(r.y);
                Erow[c + 2] = (rowdead || c + 2 == S_END) ? 0.0f : __expf(r.z);
                Erow[c + 3] = (rowdead || c + 3 == S_END) ? 0.0f : __expf(r.w);
            }
        }
        float u = (lane == S_START) ? 0.0f : NEGV;
        float Muni = 0.0f;
        eabuf[lane] = __expf(u);                 // exp(0)=1 at START, else 0

        float fr0 = fb[0 * NK], fr1 = fb[1 * NK], fr2 = fb[2 * NK], fr3 = fb[3 * NK];

        auto fstep = [&](float fc) {
            const float4* e4 = (const float4*)eabuf;
            float a0 = 0.f, a1 = 0.f, a2 = 0.f, a3 = 0.f;
            float mq[12];
            #pragma unroll
            for (int q = 0; q < 12; ++q) {
                float4 r = e4[q];
                a0 = fmaf(Erow[4 * q + 0], r.x, a0);
                a1 = fmaf(Erow[4 * q + 1], r.y, a1);
                a2 = fmaf(Erow[4 * q + 2], r.z, a2);
                a3 = fmaf(Erow[4 * q + 3], r.w, a3);
                mq[q] = fmaxf(fmaxf(r.x, r.y), fmaxf(r.z, r.w));
            }
            float acc = (a0 + a1) + (a2 + a3);   // bit-exact grouping (R1..R5)
            float m01 = fmaxf(fmaxf(mq[0], mq[1]), fmaxf(mq[2], mq[3]));
            float m23 = fmaxf(fmaxf(mq[4], mq[5]), fmaxf(mq[6], mq[7]));
            float m45 = fmaxf(fmaxf(mq[8], mq[9]), fmaxf(mq[10], mq[11]));
            float m_e = fmaxf(fmaxf(m01, m23), m45);

            float dM = __logf(m_e);              // exact stale max anchor
            u = __logf(acc) + fc - dM;
            eabuf[lane] = __expf(u);             // chain store ASAP
            Muni += dM;                          // off-chain
        };

        for (int t = 0; t < NT; t += 4) {
            { float fc = fr0; int nr = (t + 4 < NT) ? t + 4 : NT - 1; fr0 = fb[nr * NK]; fstep(fc); }
            { float fc = fr1; int nr = (t + 5 < NT) ? t + 5 : NT - 1; fr1 = fb[nr * NK]; fstep(fc); }
            { float fc = fr2; int nr = (t + 6 < NT) ? t + 6 : NT - 1; fr2 = fb[nr * NK]; fstep(fc); }
            { float fc = fr3; int nr = (t + 7 < NT) ? t + 7 : NT - 1; fr3 = fb[nr * NK]; fstep(fc); }
        }
        // logz = Muni + logsumexp(u + tEnd)
        float x = act ? (u + tEnd) : -INFINITY;
        float M2 = x;
        #pragma unroll
        for (int off = 32; off >= 1; off >>= 1)
            M2 = fmaxf(M2, __shfl_xor(M2, off, 64));
        float e = __expf(x - M2);
        #pragma unroll
        for (int off = 32; off >= 1; off >>= 1)
            e += __shfl_xor(e, off, 64);
        if (lane == 0) out[b] = Muni + M2 + __logf(e);
    } else {
        // ---------------- viterbi: exact fp32, reference op order
        float trow[NK];
        {
            const bool rowdead = (lane == S_START);
            const float4* r4 = (const float4*)(trans + LL * NK);
            #pragma unroll
            for (int q = 0; q < NK / 4; ++q) {
                float4 r = r4[q];
                const int c = 4 * q;
                trow[c + 0] = (rowdead || c + 0 == S_END) ? NEGV : r.x;
                trow[c + 1] = (rowdead || c + 1 == S_END) ? NEGV : r.y;
                trow[c + 2] = (rowdead || c + 2 == S_END) ? NEGV : r.z;
                trow[c + 3] = (rowdead || c + 3 == S_END) ? NEGV : r.w;
            }
        }
        float v = (lane == S_START) ? 0.0f : NEGV;
        vbuf[lane] = v;

        // first-occurrence argmax of s given its exact max; store to bp row.
        auto argmax_store = [&](const float (&s)[NK], float best, int row) {
            int ix[NK];
            #pragma unroll
            for (int p = 0; p < NK; ++p)
                ix[p] = (s[p] != best) ? 63 : p;
            int n16[16];
            #pragma unroll
            for (int i = 0; i < 16; ++i)
                n16[i] = min(min(ix[3 * i], ix[3 * i + 1]), ix[3 * i + 2]);
            int n6[6];
            #pragma unroll
            for (int i = 0; i < 5; ++i)
                n6[i] = min(min(n16[3 * i], n16[3 * i + 1]), n16[3 * i + 2]);
            n6[5] = n16[15];
            int bi = min(min(min(n6[0], n6[1]), n6[2]),
                         min(min(n6[3], n6[4]), n6[5]));
            bp[row * NK + LL] = (unsigned char)bi;  // lanes 47..63: same addr/value
        };

        // one pipelined step: tt = current step; sO/bestO = previous step's
        // scores+max whose argmax is deferred into this step's read window.
        auto phase = [&](float fc, int tt, float (&sN)[NK], const float (&sO)[NK],
                         float bestO) -> float {
            const float4* v4 = (const float4*)vbuf;
            float4 r[12];
            #pragma unroll
            for (int q = 0; q < 12; ++q) r[q] = v4[q];   // issue reads first
            __builtin_amdgcn_wave_barrier();             // pin reads above argmax
            argmax_store(sO, bestO, tt);                 // ~120 VALU: hides DS latency
            __builtin_amdgcn_wave_barrier();             // pin argmax above consumption
            #pragma unroll
            for (int q = 0; q < 12; ++q) {
                sN[4 * q + 0] = r[q].x + trow[4 * q + 0];
                sN[4 * q + 1] = r[q].y + trow[4 * q + 1];
                sN[4 * q + 2] = r[q].z + trow[4 * q + 2];
                sN[4 * q + 3] = r[q].w + trow[4 * q + 3];
            }
            // exact max via tree (max exactly associative; identical to np.max)
            float m16[16];
            #pragma unroll
            for (int i = 0; i < 16; ++i)
                m16[i] = fmaxf(fmaxf(sN[3 * i], sN[3 * i + 1]), sN[3 * i + 2]);
            float m6[6];
            #pragma unroll
            for (int i = 0; i < 5; ++i)
                m6[i] = fmaxf(fmaxf(m16[3 * i], m16[3 * i + 1]), m16[3 * i + 2]);
            m6[5] = m16[15];
            float best = fmaxf(fmaxf(fmaxf(m6[0], m6[1]), m6[2]),
                               fmaxf(fmaxf(m6[3], m6[4]), m6[5]));
            v = best + fc;                       // reference order: +feat after max
            vbuf[lane] = v;                      // chain store: next reads queue behind
            return best;
        };

        float sA[NK], sB[NK];
        #pragma unroll
        for (int p = 0; p < NK; ++p) sB[p] = 0.0f;   // dummy for step-0's deferral
        float bestA, bestB = 0.0f;

        float p0 = fb[0 * NK], p1 = fb[1 * NK], p2 = fb[2 * NK], p3 = fb[3 * NK];

        // peel 3 steps to align the 4-step feat-prefetch ring with the 2-phase buffer
        bestA = phase(p0, 0, sA, sB, bestB); p0 = fb[4 * NK];   // row 0 = dummy write
        bestB = phase(p1, 1, sB, sA, bestA); p1 = fb[5 * NK];
        bestA = phase(p2, 2, sA, sB, bestB); p2 = fb[6 * NK];

        for (int i = 3; i <= 1019; i += 4) {
            { bestB = phase(p3, i + 0, sB, sA, bestA); int nr = min(i + 4, NT - 1); p3 = fb[nr * NK]; }
            { bestA = phase(p0, i + 1, sA, sB, bestB); int nr = min(i + 5, NT - 1); p0 = fb[nr * NK]; }
            { bestB = phase(p1, i + 2, sB, sA, bestA); int nr = min(i + 6, NT - 1); p1 = fb[nr * NK]; }
            { bestA = phase(p2, i + 3, sA, sB, bestB); int nr = min(i + 7, NT - 1); p2 = fb[nr * NK]; }
        }
        bestB = phase(p3, 1023, sB, sA, bestA);      // last step (odd -> B)
        argmax_store(sB, bestB, 1024);               // epilogue: step 1023's argmax

        // termination: term = v + trans[END]; first-occurrence argmax
        float xv = act ? (v + tEnd) : -INFINITY;
        int idx = act ? lane : 63;
        float val = xv;
        #pragma unroll
        for (int off = 32; off >= 1; off >>= 1) {
            float ov = __shfl_xor(val, off, 64);
            int   oi = __shfl_xor(idx, off, 64);
            if (ov > val || (ov == val && oi < idx)) { val = ov; idx = oi; }
        }
        if (lane == 0) out[NB + b] = val;
        const int last = idx;

        // ---- chunk-composed backtrace; bp row for step t is t+1
        const unsigned char* bpt = bp + NK;
        __builtin_amdgcn_wave_barrier();
        int cur[NK];
        #pragma unroll
        for (int k = 0; k < NK; ++k) cur[k] = k;
        const int tbase = lane * 16;                 // 64 chunks of 16 steps
        for (int i = 15; i >= 0; --i) {
            const int t = tbase + i;
            #pragma unroll
            for (int k = 0; k < NK; ++k) cur[k] = bpt[t * NK + cur[k]];
        }
        #pragma unroll
        for (int k = 0; k < NK; ++k) comp[lane * NK + k] = (unsigned char)cur[k];
        __builtin_amdgcn_wave_barrier();

        if (lane == 0) {                             // serial chase over 64 maps
            int tag = last;
            for (int l = 63; l >= 0; --l) {
                boundary[l] = (unsigned char)tag;
                tag = comp[l * NK + tag];
            }
        }
        __builtin_amdgcn_wave_barrier();

        int tag = boundary[lane];
        float* pout = out + 2 * NB + (size_t)b * NT;
        for (int i = 15; i >= 0; --i) {              // re-expand: path[t]=tag, then step
            const int t = tbase + i;
            pout[t] = (float)tag;
            tag = bpt[t * NK + tag];
        }
    }
}

extern "C" void kernel_launch(void* const* d_in, const int* in_sizes, int n_in,
                              void* d_out, int out_size, void* d_ws, size_t ws_size,
                              hipStream_t stream) {
    (void)in_sizes; (void)n_in; (void)d_ws; (void)ws_size; (void)out_size;
    const float* feats = (const float*)d_in[0];
    const float* trans = (const float*)d_in[1];
    float* out = (float*)d_out;
    crf_fused<<<dim3(NB), dim3(128), 0, stream>>>(feats, trans, out);
}